// Round 12
// baseline (457.115 us; speedup 1.0000x reference)
//
#include <hip/hip_runtime.h>

#define N_NODES 100000
#define N_EDGES 3200000
#define BN_EPS 1e-5f
#define SCAN_BLOCKS 391   // ceil(100000/256)
#define STATS_BLOCKS 64

typedef __attribute__((ext_vector_type(8))) short short8;
typedef __attribute__((ext_vector_type(4))) float f32x4;
typedef __attribute__((ext_vector_type(4))) unsigned int uint32x4;

// workspace layout (4-byte units)
constexpr int O_STATS = 0;                      // 8 f
constexpr int O_CNT   = 8;                      // N int
constexpr int O_OFFS  = O_CNT + N_NODES;        // N int
constexpr int O_BSUM  = O_OFFS + N_NODES;       // 512 int
constexpr int O_RANK  = O_BSUM + 512;           // E int
constexpr int O_H     = O_RANK + N_EDGES;       // N*4 f
constexpr int O_H2    = O_H + 4 * N_NODES;      // N*2 f
constexpr int O_MSG   = O_H2 + 2 * N_NODES;     // E*4 f

__device__ __forceinline__ unsigned short bf16_rne(float f) {
    unsigned u = __float_as_uint(f);
    unsigned r = (u + 0x7fff + ((u >> 16) & 1)) >> 16;
    return (unsigned short)r;
}
__device__ __forceinline__ float bf16_f32(unsigned short h) {
    return __uint_as_float(((unsigned)h) << 16);
}
// hardware packed f32->bf16 RNE: dst = {hi:bf16(b), lo:bf16(a)}
__device__ __forceinline__ unsigned cvtpk_bf16(float a, float b) {
    unsigned r;
    asm("v_cvt_pk_bf16_f32 %0, %1, %2" : "=v"(r) : "v"(a), "v"(b));
    return r;
}
union PackU { uint32x4 u; short8 s; };

__global__ __launch_bounds__(256) void bn_stats_kernel(const float* __restrict__ x,
                                                       float* __restrict__ stats) {
    __shared__ float red[4][8];
    int tid = threadIdx.x;
    float s0=0.f,s1=0.f,s2=0.f,s3=0.f,q0=0.f,q1=0.f,q2=0.f,q3=0.f;
    for (int i = blockIdx.x * 256 + tid; i < N_NODES; i += STATS_BLOCKS * 256) {
        float4 v = reinterpret_cast<const float4*>(x)[i];
        s0+=v.x; s1+=v.y; s2+=v.z; s3+=v.w;
        q0=fmaf(v.x,v.x,q0); q1=fmaf(v.y,v.y,q1); q2=fmaf(v.z,v.z,q2); q3=fmaf(v.w,v.w,q3);
    }
    #pragma unroll
    for (int off = 32; off > 0; off >>= 1) {
        s0 += __shfl_down(s0, off); s1 += __shfl_down(s1, off);
        s2 += __shfl_down(s2, off); s3 += __shfl_down(s3, off);
        q0 += __shfl_down(q0, off); q1 += __shfl_down(q1, off);
        q2 += __shfl_down(q2, off); q3 += __shfl_down(q3, off);
    }
    int wave = tid >> 6, lane = tid & 63;
    if (lane == 0) {
        red[wave][0]=s0; red[wave][1]=s1; red[wave][2]=s2; red[wave][3]=s3;
        red[wave][4]=q0; red[wave][5]=q1; red[wave][6]=q2; red[wave][7]=q3;
    }
    __syncthreads();
    if (tid < 8) {
        float v = red[0][tid] + red[1][tid] + red[2][tid] + red[3][tid];
        atomicAdd(&stats[tid], v);
    }
}

__global__ void bn_apply_kernel(const float* __restrict__ x,
                                const float* __restrict__ stats,
                                const float* __restrict__ gamma,
                                const float* __restrict__ beta,
                                float* __restrict__ h) {
    int i = blockIdx.x * blockDim.x + threadIdx.x;
    if (i >= N_NODES) return;
    const float inv_n = 1.0f / (float)N_NODES;
    float m0 = stats[0]*inv_n, m1 = stats[1]*inv_n, m2 = stats[2]*inv_n, m3 = stats[3]*inv_n;
    float sc0 = rsqrtf(stats[4]*inv_n - m0*m0 + BN_EPS) * gamma[0];
    float sc1 = rsqrtf(stats[5]*inv_n - m1*m1 + BN_EPS) * gamma[1];
    float sc2 = rsqrtf(stats[6]*inv_n - m2*m2 + BN_EPS) * gamma[2];
    float sc3 = rsqrtf(stats[7]*inv_n - m3*m3 + BN_EPS) * gamma[3];
    float4 v = reinterpret_cast<const float4*>(x)[i];
    float4 o;
    o.x = (v.x - m0) * sc0 + beta[0];
    o.y = (v.y - m1) * sc1 + beta[1];
    o.z = (v.z - m2) * sc2 + beta[2];
    o.w = (v.w - m3) * sc3 + beta[3];
    reinterpret_cast<float4*>(h)[i] = o;
}

__global__ void rank_kernel(const int* __restrict__ ei, int* __restrict__ cnt,
                            int* __restrict__ rank) {
    int e = blockIdx.x * 256 + threadIdx.x;
    if (e >= N_EDGES) return;
    int d = ei[N_EDGES + e];
    rank[e] = atomicAdd(&cnt[d], 1);
}

__global__ void scan_block_kernel(const int* __restrict__ cnt, int* __restrict__ offs,
                                  int* __restrict__ bsums) {
    __shared__ int sd[256];
    int t = threadIdx.x;
    int i = blockIdx.x * 256 + t;
    int v = (i < N_NODES) ? cnt[i] : 0;
    sd[t] = v; __syncthreads();
    for (int o = 1; o < 256; o <<= 1) {
        int x = (t >= o) ? sd[t - o] : 0;
        __syncthreads();
        sd[t] += x;
        __syncthreads();
    }
    if (i < N_NODES) offs[i] = sd[t] - v;
    if (t == 255) bsums[blockIdx.x] = sd[255];
}

__global__ void scan_mid_kernel(int* __restrict__ bsums) {
    __shared__ int sd[512];
    int t = threadIdx.x;
    int v = (t < SCAN_BLOCKS) ? bsums[t] : 0;
    sd[t] = v; __syncthreads();
    for (int o = 1; o < 512; o <<= 1) {
        int x = (t >= o) ? sd[t - o] : 0;
        __syncthreads();
        sd[t] += x;
        __syncthreads();
    }
    if (t < SCAN_BLOCKS) bsums[t] = sd[t] - v;
}

__global__ void scan_add_kernel(int* __restrict__ offs, const int* __restrict__ bsums) {
    int i = blockIdx.x * 256 + threadIdx.x;
    if (i < N_NODES) offs[i] += bsums[blockIdx.x];
}

// conv1: 2 tiles/wave (32 edges), LDS 16.9KB/block -> 8 blocks/CU.
// Layer-1 in-register, A bf16-hi (error averaged by agg1 mean), B hi/lo split.
// Epilogue: lane handles edge lane&31, feature-half (lane>>5)*16, shfl_xor(32) combine.
__global__ __launch_bounds__(256, 2) void conv1_mfma_kernel(
    const float* __restrict__ h,
    const int* __restrict__ ei, const int* __restrict__ rank, const int* __restrict__ offs,
    const float* __restrict__ w1, const float* __restrict__ b1,
    const float* __restrict__ w2, const float* __restrict__ b2,
    const float* __restrict__ w3, const float* __restrict__ b3,
    float* __restrict__ msg)
{
    __shared__ float a2lds[4][32 * 33];   // 16.9 KB
    int tid = threadIdx.x;
    int wave = tid >> 6, lane = tid & 63;
    int kg = lane >> 4, fr = lane & 15;
    float* lds = &a2lds[wave][0];

    int base = (blockIdx.x * 4 + wave) * 32;

    // prefetch: indices, 4 node gathers in flight, epilogue rank/offs
    int e0 = base + fr, e1 = base + 16 + fr;
    int dd0 = ei[N_EDGES + e0], dd1 = ei[N_EDGES + e1];
    int ss0 = ei[e0], ss1 = ei[e1];
    int el = lane & 31;
    int rk = rank[base + el];
    int d_save = ((lane >> 4) & 1) ? dd1 : dd0;
    int ofs = offs[d_save];

    const float4* h4 = reinterpret_cast<const float4*>(h);
    float4 xi0 = h4[dd0], xj0 = h4[ss0];
    float4 xi1 = h4[dd1], xj1 = h4[ss1];

    // layer-1 coefficient slices for k = kg*8+i
    float al[4][8], be[4][8], b1v[8];
    #pragma unroll
    for (int i = 0; i < 8; i++) {
        int k = kg * 8 + i;
        #pragma unroll
        for (int c = 0; c < 4; c++) {
            float wa = w1[c * 32 + k];
            float wb = w1[(4 + c) * 32 + k];
            al[c][i] = wa - wb;
            be[c][i] = wb;
        }
        b1v[i] = b1[k];
    }
    short8 bhi0, blo0, bhi1, blo1;
    #pragma unroll
    for (int i = 0; i < 8; i++) {
        int k = kg * 8 + i;
        float w0 = w2[k * 32 + fr];
        float w1c = w2[k * 32 + fr + 16];
        unsigned short h0 = bf16_rne(w0);
        bhi0[i] = (short)h0; blo0[i] = (short)bf16_rne(w0 - bf16_f32(h0));
        unsigned short h1 = bf16_rne(w1c);
        bhi1[i] = (short)h1; blo1[i] = (short)bf16_rne(w1c - bf16_f32(h1));
    }
    float b2v0 = b2[fr], b2v1 = b2[fr + 16];

    #pragma unroll
    for (int t = 0; t < 2; t++) {
        float4 xi = t == 0 ? xi0 : xi1;
        float4 xj = t == 0 ? xj0 : xj1;
        float a[8];
        #pragma unroll
        for (int i = 0; i < 8; i++) {
            float pre = b1v[i];
            pre = fmaf(al[0][i], xi.x, pre);
            pre = fmaf(al[1][i], xi.y, pre);
            pre = fmaf(al[2][i], xi.z, pre);
            pre = fmaf(al[3][i], xi.w, pre);
            pre = fmaf(be[0][i], xj.x, pre);
            pre = fmaf(be[1][i], xj.y, pre);
            pre = fmaf(be[2][i], xj.z, pre);
            pre = fmaf(be[3][i], xj.w, pre);
            a[i] = fmaxf(pre, 0.f);
        }
        PackU pu;
        #pragma unroll
        for (int j = 0; j < 4; j++) pu.u[j] = cvtpk_bf16(a[2*j], a[2*j+1]);
        short8 ahi = pu.s;

        f32x4 acc0 = {0.f, 0.f, 0.f, 0.f}, acc1 = {0.f, 0.f, 0.f, 0.f};
        acc0 = __builtin_amdgcn_mfma_f32_16x16x32_bf16(ahi, blo0, acc0, 0, 0, 0);
        acc0 = __builtin_amdgcn_mfma_f32_16x16x32_bf16(ahi, bhi0, acc0, 0, 0, 0);
        acc1 = __builtin_amdgcn_mfma_f32_16x16x32_bf16(ahi, blo1, acc1, 0, 0, 0);
        acc1 = __builtin_amdgcn_mfma_f32_16x16x32_bf16(ahi, bhi1, acc1, 0, 0, 0);
        #pragma unroll
        for (int r = 0; r < 4; r++) {
            int er = t * 16 + kg * 4 + r;    // 0..31
            lds[er * 33 + fr]      = fmaxf(acc0[r] + b2v0, 0.f);
            lds[er * 33 + fr + 16] = fmaxf(acc1[r] + b2v1, 0.f);
        }
    }
    asm volatile("s_waitcnt lgkmcnt(0)" ::: "memory");

    // epilogue: lane covers features j0..j0+15 of edge el
    int j0 = (lane >> 5) * 16;
    const float2* w3f2 = reinterpret_cast<const float2*>(w3);
    float m0 = 0.f, m1 = 0.f;
    #pragma unroll
    for (int j = 0; j < 16; j++) {
        float aj = lds[el * 33 + j0 + j];
        float2 w = w3f2[j0 + j];
        m0 = fmaf(aj, w.x, m0);
        m1 = fmaf(aj, w.y, m1);
    }
    m0 += __shfl_xor(m0, 32);
    m1 += __shfl_xor(m1, 32);
    if (lane < 32) {
        m0 = fmaxf(m0 + b3[0], 0.f);
        m1 = fmaxf(m1 + b3[1], 0.f);
        reinterpret_cast<float2*>(msg)[ofs + rk] = make_float2(m0, m1);
    }
}

__global__ void agg1_kernel(const float* __restrict__ msg, const int* __restrict__ offs,
                            const int* __restrict__ cnt, float* __restrict__ h2) {
    int lane = threadIdx.x & 63;
    int wave = threadIdx.x >> 6;
    int node = blockIdx.x * 8 + wave * 2 + (lane >> 5);
    int sub = lane & 31;
    if (node >= N_NODES) return;
    int base = offs[node];
    int deg  = cnt[node];
    float s0 = 0.f, s1 = 0.f;
    for (int k = sub; k < deg; k += 32) {
        float2 m = reinterpret_cast<const float2*>(msg)[base + k];
        s0 += m.x; s1 += m.y;
    }
    #pragma unroll
    for (int o = 16; o > 0; o >>= 1) {
        s0 += __shfl_down(s0, o, 32);
        s1 += __shfl_down(s1, o, 32);
    }
    if (sub == 0) {
        float c = fmaxf((float)deg, 1.f);
        reinterpret_cast<float2*>(h2)[node] = make_float2(s0 / c, s1 / c);
    }
}

// conv2: same 2-tile structure; A full hi/lo split; float4 output, no final relu.
__global__ __launch_bounds__(256, 2) void conv2_mfma_kernel(
    const float* __restrict__ h2,
    const int* __restrict__ ei, const int* __restrict__ rank, const int* __restrict__ offs,
    const float* __restrict__ w1, const float* __restrict__ b1,
    const float* __restrict__ w2, const float* __restrict__ b2,
    const float* __restrict__ w3, const float* __restrict__ b3,
    float* __restrict__ msg)
{
    __shared__ float a2lds[4][32 * 33];
    int tid = threadIdx.x;
    int wave = tid >> 6, lane = tid & 63;
    int kg = lane >> 4, fr = lane & 15;
    float* lds = &a2lds[wave][0];

    int base = (blockIdx.x * 4 + wave) * 32;

    int e0 = base + fr, e1 = base + 16 + fr;
    int dd0 = ei[N_EDGES + e0], dd1 = ei[N_EDGES + e1];
    int ss0 = ei[e0], ss1 = ei[e1];
    int el = lane & 31;
    int rk = rank[base + el];
    int d_save = ((lane >> 4) & 1) ? dd1 : dd0;
    int ofs = offs[d_save];

    const float2* h2v = reinterpret_cast<const float2*>(h2);
    float2 yd0 = h2v[dd0], ys0 = h2v[ss0];
    float2 yd1 = h2v[dd1], ys1 = h2v[ss1];

    float al0[8], al1[8], be0[8], be1[8], b1v[8];
    #pragma unroll
    for (int i = 0; i < 8; i++) {
        int k = kg * 8 + i;
        float c0a = w1[k], c1a = w1[32 + k];
        float c0b = w1[64 + k], c1b = w1[96 + k];
        al0[i] = c0a - c0b; al1[i] = c1a - c1b;
        be0[i] = c0b; be1[i] = c1b;
        b1v[i] = b1[k];
    }
    short8 bhi0, blo0, bhi1, blo1;
    #pragma unroll
    for (int i = 0; i < 8; i++) {
        int k = kg * 8 + i;
        float w0 = w2[k * 32 + fr];
        float w1c = w2[k * 32 + fr + 16];
        unsigned short h0 = bf16_rne(w0);
        bhi0[i] = (short)h0; blo0[i] = (short)bf16_rne(w0 - bf16_f32(h0));
        unsigned short h1 = bf16_rne(w1c);
        bhi1[i] = (short)h1; blo1[i] = (short)bf16_rne(w1c - bf16_f32(h1));
    }
    float b2v0 = b2[fr], b2v1 = b2[fr + 16];

    #pragma unroll
    for (int t = 0; t < 2; t++) {
        float2 yd = t == 0 ? yd0 : yd1;
        float2 ys = t == 0 ? ys0 : ys1;
        float a[8];
        #pragma unroll
        for (int i = 0; i < 8; i++) {
            float pre = b1v[i];
            pre = fmaf(al0[i], yd.x, pre);
            pre = fmaf(al1[i], yd.y, pre);
            pre = fmaf(be0[i], ys.x, pre);
            pre = fmaf(be1[i], ys.y, pre);
            a[i] = fmaxf(pre, 0.f);
        }
        PackU ph, pl;
        #pragma unroll
        for (int j = 0; j < 4; j++) ph.u[j] = cvtpk_bf16(a[2*j], a[2*j+1]);
        #pragma unroll
        for (int j = 0; j < 4; j++) {
            float hlo = __uint_as_float(ph.u[j] << 16);
            float hhi = __uint_as_float(ph.u[j] & 0xffff0000u);
            pl.u[j] = cvtpk_bf16(a[2*j] - hlo, a[2*j+1] - hhi);
        }
        short8 ahi = ph.s, alo = pl.s;

        f32x4 acc0 = {0.f, 0.f, 0.f, 0.f}, acc1 = {0.f, 0.f, 0.f, 0.f};
        acc0 = __builtin_amdgcn_mfma_f32_16x16x32_bf16(alo, bhi0, acc0, 0, 0, 0);
        acc0 = __builtin_amdgcn_mfma_f32_16x16x32_bf16(ahi, blo0, acc0, 0, 0, 0);
        acc0 = __builtin_amdgcn_mfma_f32_16x16x32_bf16(ahi, bhi0, acc0, 0, 0, 0);
        acc1 = __builtin_amdgcn_mfma_f32_16x16x32_bf16(alo, bhi1, acc1, 0, 0, 0);
        acc1 = __builtin_amdgcn_mfma_f32_16x16x32_bf16(ahi, blo1, acc1, 0, 0, 0);
        acc1 = __builtin_amdgcn_mfma_f32_16x16x32_bf16(ahi, bhi1, acc1, 0, 0, 0);
        #pragma unroll
        for (int r = 0; r < 4; r++) {
            int er = t * 16 + kg * 4 + r;
            lds[er * 33 + fr]      = fmaxf(acc0[r] + b2v0, 0.f);
            lds[er * 33 + fr + 16] = fmaxf(acc1[r] + b2v1, 0.f);
        }
    }
    asm volatile("s_waitcnt lgkmcnt(0)" ::: "memory");

    int j0 = (lane >> 5) * 16;
    const float4* w3f4 = reinterpret_cast<const float4*>(w3);
    float o0 = 0.f, o1 = 0.f, o2 = 0.f, o3 = 0.f;
    #pragma unroll
    for (int j = 0; j < 16; j++) {
        float aj = lds[el * 33 + j0 + j];
        float4 w = w3f4[j0 + j];
        o0 = fmaf(aj, w.x, o0);
        o1 = fmaf(aj, w.y, o1);
        o2 = fmaf(aj, w.z, o2);
        o3 = fmaf(aj, w.w, o3);
    }
    o0 += __shfl_xor(o0, 32); o1 += __shfl_xor(o1, 32);
    o2 += __shfl_xor(o2, 32); o3 += __shfl_xor(o3, 32);
    if (lane < 32) {
        reinterpret_cast<float4*>(msg)[ofs + rk] =
            make_float4(o0 + b3[0], o1 + b3[1], o2 + b3[2], o3 + b3[3]);
    }
}

__global__ void agg2_kernel(const float* __restrict__ msg, const int* __restrict__ offs,
                            const int* __restrict__ cnt, float* __restrict__ out) {
    int lane = threadIdx.x & 63;
    int wave = threadIdx.x >> 6;
    int node = blockIdx.x * 8 + wave * 2 + (lane >> 5);
    int sub = lane & 31;
    if (node >= N_NODES) return;
    int base = offs[node];
    int deg  = cnt[node];
    float s0 = 0.f, s1 = 0.f, s2 = 0.f, s3 = 0.f;
    for (int k = sub; k < deg; k += 32) {
        float4 m = reinterpret_cast<const float4*>(msg)[base + k];
        s0 += m.x; s1 += m.y; s2 += m.z; s3 += m.w;
    }
    #pragma unroll
    for (int o = 16; o > 0; o >>= 1) {
        s0 += __shfl_down(s0, o, 32); s1 += __shfl_down(s1, o, 32);
        s2 += __shfl_down(s2, o, 32); s3 += __shfl_down(s3, o, 32);
    }
    if (sub == 0) {
        float c = fmaxf((float)deg, 1.f);
        reinterpret_cast<float4*>(out)[node] = make_float4(s0/c, s1/c, s2/c, s3/c);
    }
}

extern "C" void kernel_launch(void* const* d_in, const int* in_sizes, int n_in,
                              void* d_out, int out_size, void* d_ws, size_t ws_size,
                              hipStream_t stream) {
    const float* x        = (const float*)d_in[0];
    const int*   ei       = (const int*)  d_in[1];
    const float* bn_gamma = (const float*)d_in[2];
    const float* bn_beta  = (const float*)d_in[3];
    const float* enc_w1   = (const float*)d_in[4];
    const float* enc_b1   = (const float*)d_in[5];
    const float* enc_w2   = (const float*)d_in[6];
    const float* enc_b2   = (const float*)d_in[7];
    const float* enc_w3   = (const float*)d_in[8];
    const float* enc_b3   = (const float*)d_in[9];
    const float* dec_w1   = (const float*)d_in[10];
    const float* dec_b1   = (const float*)d_in[11];
    const float* dec_w2   = (const float*)d_in[12];
    const float* dec_b2   = (const float*)d_in[13];
    const float* dec_w3   = (const float*)d_in[14];
    const float* dec_b3   = (const float*)d_in[15];

    float* wsf   = (float*)d_ws;
    int*   wsi   = (int*)d_ws;
    float* stats = wsf + O_STATS;
    int*   cnt   = wsi + O_CNT;
    int*   offs  = wsi + O_OFFS;
    int*   bsums = wsi + O_BSUM;
    int*   rank  = wsi + O_RANK;
    float* h     = wsf + O_H;
    float* h2    = wsf + O_H2;
    float* msg   = wsf + O_MSG;
    float* out   = (float*)d_out;

    hipMemsetAsync(d_ws, 0, (size_t)(8 + N_NODES) * sizeof(float), stream);

    const int nodeBlocks = (N_NODES + 255) / 256;
    const int convBlocks = N_EDGES / 128;            // 25000, 128 edges/block
    const int edgeBlocks = (N_EDGES + 255) / 256;
    const int aggBlocks  = (N_NODES + 7) / 8;

    bn_stats_kernel<<<STATS_BLOCKS, 256, 0, stream>>>(x, stats);
    bn_apply_kernel<<<nodeBlocks, 256, 0, stream>>>(x, stats, bn_gamma, bn_beta, h);
    rank_kernel<<<edgeBlocks, 256, 0, stream>>>(ei, cnt, rank);
    scan_block_kernel<<<SCAN_BLOCKS, 256, 0, stream>>>(cnt, offs, bsums);
    scan_mid_kernel<<<1, 512, 0, stream>>>(bsums);
    scan_add_kernel<<<SCAN_BLOCKS, 256, 0, stream>>>(offs, bsums);
    conv1_mfma_kernel<<<convBlocks, 256, 0, stream>>>(h, ei, rank, offs,
                                                      enc_w1, enc_b1, enc_w2, enc_b2,
                                                      enc_w3, enc_b3, msg);
    agg1_kernel<<<aggBlocks, 256, 0, stream>>>(msg, offs, cnt, h2);
    conv2_mfma_kernel<<<convBlocks, 256, 0, stream>>>(h2, ei, rank, offs,
                                                      dec_w1, dec_b1, dec_w2, dec_b2,
                                                      dec_w3, dec_b3, msg);
    agg2_kernel<<<aggBlocks, 256, 0, stream>>>(msg, offs, cnt, out);
}

// Round 13
// 341.218 us; speedup vs baseline: 1.3397x; 1.3397x over previous
//
#include <hip/hip_runtime.h>

#define N_NODES 100000
#define N_EDGES 3200000
#define BN_EPS 1e-5f
#define SCAN_BLOCKS 391   // ceil(100000/256)
#define STATS_BLOCKS 64
#define CONV_BLOCKS 1024
#define NGROUPS (N_EDGES / 64)        // 50000
#define GSTRIDE (CONV_BLOCKS * 4)     // 4096

typedef __attribute__((ext_vector_type(8))) short short8;
typedef __attribute__((ext_vector_type(4))) float f32x4;
typedef __attribute__((ext_vector_type(4))) unsigned int uint32x4;

// workspace layout (4-byte units)
constexpr int O_STATS = 0;                      // 8 f
constexpr int O_CNT   = 8;                      // N int
constexpr int O_OFFS  = O_CNT + N_NODES;        // N int
constexpr int O_BSUM  = O_OFFS + N_NODES;       // 512 int
constexpr int O_RANK  = O_BSUM + 512;           // E int
constexpr int O_H     = O_RANK + N_EDGES;       // N*4 f
constexpr int O_H2    = O_H + 4 * N_NODES;      // N*2 f
constexpr int O_MSG   = O_H2 + 2 * N_NODES;     // E*4 f

__device__ __forceinline__ unsigned short bf16_rne(float f) {
    unsigned u = __float_as_uint(f);
    unsigned r = (u + 0x7fff + ((u >> 16) & 1)) >> 16;
    return (unsigned short)r;
}
__device__ __forceinline__ float bf16_f32(unsigned short h) {
    return __uint_as_float(((unsigned)h) << 16);
}
__device__ __forceinline__ unsigned cvtpk_bf16(float a, float b) {
    unsigned r;
    asm("v_cvt_pk_bf16_f32 %0, %1, %2" : "=v"(r) : "v"(a), "v"(b));
    return r;
}
union PackU { uint32x4 u; short8 s; };

__global__ __launch_bounds__(256) void bn_stats_kernel(const float* __restrict__ x,
                                                       float* __restrict__ stats) {
    __shared__ float red[4][8];
    int tid = threadIdx.x;
    float s0=0.f,s1=0.f,s2=0.f,s3=0.f,q0=0.f,q1=0.f,q2=0.f,q3=0.f;
    for (int i = blockIdx.x * 256 + tid; i < N_NODES; i += STATS_BLOCKS * 256) {
        float4 v = reinterpret_cast<const float4*>(x)[i];
        s0+=v.x; s1+=v.y; s2+=v.z; s3+=v.w;
        q0=fmaf(v.x,v.x,q0); q1=fmaf(v.y,v.y,q1); q2=fmaf(v.z,v.z,q2); q3=fmaf(v.w,v.w,q3);
    }
    #pragma unroll
    for (int off = 32; off > 0; off >>= 1) {
        s0 += __shfl_down(s0, off); s1 += __shfl_down(s1, off);
        s2 += __shfl_down(s2, off); s3 += __shfl_down(s3, off);
        q0 += __shfl_down(q0, off); q1 += __shfl_down(q1, off);
        q2 += __shfl_down(q2, off); q3 += __shfl_down(q3, off);
    }
    int wave = tid >> 6, lane = tid & 63;
    if (lane == 0) {
        red[wave][0]=s0; red[wave][1]=s1; red[wave][2]=s2; red[wave][3]=s3;
        red[wave][4]=q0; red[wave][5]=q1; red[wave][6]=q2; red[wave][7]=q3;
    }
    __syncthreads();
    if (tid < 8) {
        float v = red[0][tid] + red[1][tid] + red[2][tid] + red[3][tid];
        atomicAdd(&stats[tid], v);
    }
}

__global__ void bn_apply_kernel(const float* __restrict__ x,
                                const float* __restrict__ stats,
                                const float* __restrict__ gamma,
                                const float* __restrict__ beta,
                                float* __restrict__ h) {
    int i = blockIdx.x * blockDim.x + threadIdx.x;
    if (i >= N_NODES) return;
    const float inv_n = 1.0f / (float)N_NODES;
    float m0 = stats[0]*inv_n, m1 = stats[1]*inv_n, m2 = stats[2]*inv_n, m3 = stats[3]*inv_n;
    float sc0 = rsqrtf(stats[4]*inv_n - m0*m0 + BN_EPS) * gamma[0];
    float sc1 = rsqrtf(stats[5]*inv_n - m1*m1 + BN_EPS) * gamma[1];
    float sc2 = rsqrtf(stats[6]*inv_n - m2*m2 + BN_EPS) * gamma[2];
    float sc3 = rsqrtf(stats[7]*inv_n - m3*m3 + BN_EPS) * gamma[3];
    float4 v = reinterpret_cast<const float4*>(x)[i];
    float4 o;
    o.x = (v.x - m0) * sc0 + beta[0];
    o.y = (v.y - m1) * sc1 + beta[1];
    o.z = (v.z - m2) * sc2 + beta[2];
    o.w = (v.w - m3) * sc3 + beta[3];
    reinterpret_cast<float4*>(h)[i] = o;
}

__global__ void rank_kernel(const int* __restrict__ ei, int* __restrict__ cnt,
                            int* __restrict__ rank) {
    int e = blockIdx.x * 256 + threadIdx.x;
    if (e >= N_EDGES) return;
    int d = ei[N_EDGES + e];
    rank[e] = atomicAdd(&cnt[d], 1);
}

__global__ void scan_block_kernel(const int* __restrict__ cnt, int* __restrict__ offs,
                                  int* __restrict__ bsums) {
    __shared__ int sd[256];
    int t = threadIdx.x;
    int i = blockIdx.x * 256 + t;
    int v = (i < N_NODES) ? cnt[i] : 0;
    sd[t] = v; __syncthreads();
    for (int o = 1; o < 256; o <<= 1) {
        int x = (t >= o) ? sd[t - o] : 0;
        __syncthreads();
        sd[t] += x;
        __syncthreads();
    }
    if (i < N_NODES) offs[i] = sd[t] - v;
    if (t == 255) bsums[blockIdx.x] = sd[255];
}

__global__ void scan_mid_kernel(int* __restrict__ bsums) {
    __shared__ int sd[512];
    int t = threadIdx.x;
    int v = (t < SCAN_BLOCKS) ? bsums[t] : 0;
    sd[t] = v; __syncthreads();
    for (int o = 1; o < 512; o <<= 1) {
        int x = (t >= o) ? sd[t - o] : 0;
        __syncthreads();
        sd[t] += x;
        __syncthreads();
    }
    if (t < SCAN_BLOCKS) bsums[t] = sd[t] - v;
}

__global__ void scan_add_kernel(int* __restrict__ offs, const int* __restrict__ bsums) {
    int i = blockIdx.x * 256 + threadIdx.x;
    if (i < N_NODES) offs[i] += bsums[blockIdx.x];
}

// conv1: PERSISTENT waves, 64 edges/group, ~12 groups/wave.
// Weight setup once/wave. Pipeline: next-idx before compute, next-gather after
// compute (recycled regs), epilogue hides gather latency.
__global__ __launch_bounds__(256) void conv1_mfma_kernel(
    const float* __restrict__ h,
    const int* __restrict__ ei, const int* __restrict__ rank, const int* __restrict__ offs,
    const float* __restrict__ w1, const float* __restrict__ b1,
    const float* __restrict__ w2, const float* __restrict__ b2,
    const float* __restrict__ w3, const float* __restrict__ b3,
    float* __restrict__ msg)
{
    __shared__ float a2lds[4][64 * 33];   // 33.8 KB
    int tid = threadIdx.x;
    int wave = tid >> 6, lane = tid & 63;
    int kg = lane >> 4, fr = lane & 15;
    float* lds = &a2lds[wave][0];
    const float4* h4 = reinterpret_cast<const float4*>(h);

    // ---- weight setup, ONCE per wave ----
    float al[4][8], be[4][8], b1v[8];
    #pragma unroll
    for (int i = 0; i < 8; i++) {
        int k = kg * 8 + i;
        #pragma unroll
        for (int c = 0; c < 4; c++) {
            float wa = w1[c * 32 + k];
            float wb = w1[(4 + c) * 32 + k];
            al[c][i] = wa - wb;
            be[c][i] = wb;
        }
        b1v[i] = b1[k];
    }
    short8 bhi0, blo0, bhi1, blo1;
    #pragma unroll
    for (int i = 0; i < 8; i++) {
        int k = kg * 8 + i;
        float w0 = w2[k * 32 + fr];
        float w1c = w2[k * 32 + fr + 16];
        unsigned short h0 = bf16_rne(w0);
        bhi0[i] = (short)h0; blo0[i] = (short)bf16_rne(w0 - bf16_f32(h0));
        unsigned short h1 = bf16_rne(w1c);
        bhi1[i] = (short)h1; blo1[i] = (short)bf16_rne(w1c - bf16_f32(h1));
    }
    float b2v0 = b2[fr], b2v1 = b2[fr + 16];

    int g = blockIdx.x * 4 + wave;

    // ---- prologue: group g loads ----
    int base = g * 64;
    int dd0, dd1, dd2, dd3, ss0, ss1, ss2, ss3;
    {
        int e0 = base + fr, e1 = base + 16 + fr, e2 = base + 32 + fr, e3 = base + 48 + fr;
        dd0 = ei[N_EDGES + e0]; dd1 = ei[N_EDGES + e1];
        dd2 = ei[N_EDGES + e2]; dd3 = ei[N_EDGES + e3];
        ss0 = ei[e0]; ss1 = ei[e1]; ss2 = ei[e2]; ss3 = ei[e3];
    }
    int rk = rank[base + lane];
    int dsv = kg == 0 ? dd0 : kg == 1 ? dd1 : kg == 2 ? dd2 : dd3;
    int ofs = offs[dsv];
    float4 xi0 = h4[dd0], xj0 = h4[ss0];
    float4 xi1 = h4[dd1], xj1 = h4[ss1];
    float4 xi2 = h4[dd2], xj2 = h4[ss2];
    float4 xi3 = h4[dd3], xj3 = h4[ss3];

    while (true) {
        int gn = g + GSTRIDE;
        bool hn = gn < NGROUPS;
        int basen = gn * 64;
        int nrk = 0, nofs = 0;
        // next-group indices (dd/ss recycled after gathers consumed them... they
        // are consumed only via xi/xj; safe to load into fresh names)
        int ndd0=0,ndd1=0,ndd2=0,ndd3=0,nss0=0,nss1=0,nss2=0,nss3=0;
        if (hn) {
            int f0 = basen + fr, f1 = basen + 16 + fr, f2 = basen + 32 + fr, f3 = basen + 48 + fr;
            ndd0 = ei[N_EDGES + f0]; ndd1 = ei[N_EDGES + f1];
            ndd2 = ei[N_EDGES + f2]; ndd3 = ei[N_EDGES + f3];
            nss0 = ei[f0]; nss1 = ei[f1]; nss2 = ei[f2]; nss3 = ei[f3];
            nrk = rank[basen + lane];
        }

        // ---- compute 4 tiles (consumes xi/xj) ----
        #pragma unroll
        for (int t = 0; t < 4; t++) {
            float4 xi = t == 0 ? xi0 : t == 1 ? xi1 : t == 2 ? xi2 : xi3;
            float4 xj = t == 0 ? xj0 : t == 1 ? xj1 : t == 2 ? xj2 : xj3;
            float a[8];
            #pragma unroll
            for (int i = 0; i < 8; i++) {
                float pre = b1v[i];
                pre = fmaf(al[0][i], xi.x, pre);
                pre = fmaf(al[1][i], xi.y, pre);
                pre = fmaf(al[2][i], xi.z, pre);
                pre = fmaf(al[3][i], xi.w, pre);
                pre = fmaf(be[0][i], xj.x, pre);
                pre = fmaf(be[1][i], xj.y, pre);
                pre = fmaf(be[2][i], xj.z, pre);
                pre = fmaf(be[3][i], xj.w, pre);
                a[i] = fmaxf(pre, 0.f);
            }
            PackU pu;
            #pragma unroll
            for (int j = 0; j < 4; j++) pu.u[j] = cvtpk_bf16(a[2*j], a[2*j+1]);
            short8 ahi = pu.s;

            f32x4 acc0 = {0.f, 0.f, 0.f, 0.f}, acc1 = {0.f, 0.f, 0.f, 0.f};
            acc0 = __builtin_amdgcn_mfma_f32_16x16x32_bf16(ahi, blo0, acc0, 0, 0, 0);
            acc0 = __builtin_amdgcn_mfma_f32_16x16x32_bf16(ahi, bhi0, acc0, 0, 0, 0);
            acc1 = __builtin_amdgcn_mfma_f32_16x16x32_bf16(ahi, blo1, acc1, 0, 0, 0);
            acc1 = __builtin_amdgcn_mfma_f32_16x16x32_bf16(ahi, bhi1, acc1, 0, 0, 0);
            #pragma unroll
            for (int r = 0; r < 4; r++) {
                int er = t * 16 + kg * 4 + r;
                lds[er * 33 + fr]      = fmaxf(acc0[r] + b2v0, 0.f);
                lds[er * 33 + fr + 16] = fmaxf(acc1[r] + b2v1, 0.f);
            }
        }

        // ---- next-group gathers into recycled regs ----
        if (hn) {
            xi0 = h4[ndd0]; xj0 = h4[nss0];
            xi1 = h4[ndd1]; xj1 = h4[nss1];
            xi2 = h4[ndd2]; xj2 = h4[nss2];
            xi3 = h4[ndd3]; xj3 = h4[nss3];
            int ndsv = kg == 0 ? ndd0 : kg == 1 ? ndd1 : kg == 2 ? ndd2 : ndd3;
            nofs = offs[ndsv];
        }

        asm volatile("s_waitcnt lgkmcnt(0)" ::: "memory");

        // ---- epilogue: lane covers edge `lane`, all 32 features ----
        float m0 = b3[0], m1 = b3[1];
        #pragma unroll
        for (int j = 0; j < 32; j++) {
            float aj = lds[lane * 33 + j];
            m0 = fmaf(aj, w3[2 * j], m0);
            m1 = fmaf(aj, w3[2 * j + 1], m1);
        }
        m0 = fmaxf(m0, 0.f); m1 = fmaxf(m1, 0.f);
        reinterpret_cast<float2*>(msg)[ofs + rk] = make_float2(m0, m1);

        if (!hn) break;
        rk = nrk; ofs = nofs; g = gn;
    }
}

__global__ void agg1_kernel(const float* __restrict__ msg, const int* __restrict__ offs,
                            const int* __restrict__ cnt, float* __restrict__ h2) {
    int lane = threadIdx.x & 63;
    int wave = threadIdx.x >> 6;
    int node = blockIdx.x * 8 + wave * 2 + (lane >> 5);
    int sub = lane & 31;
    if (node >= N_NODES) return;
    int base = offs[node];
    int deg  = cnt[node];
    float s0 = 0.f, s1 = 0.f;
    for (int k = sub; k < deg; k += 32) {
        float2 m = reinterpret_cast<const float2*>(msg)[base + k];
        s0 += m.x; s1 += m.y;
    }
    #pragma unroll
    for (int o = 16; o > 0; o >>= 1) {
        s0 += __shfl_down(s0, o, 32);
        s1 += __shfl_down(s1, o, 32);
    }
    if (sub == 0) {
        float c = fmaxf((float)deg, 1.f);
        reinterpret_cast<float2*>(h2)[node] = make_float2(s0 / c, s1 / c);
    }
}

// conv2: persistent, same pipeline; A full hi/lo split; float4 output.
__global__ __launch_bounds__(256) void conv2_mfma_kernel(
    const float* __restrict__ h2,
    const int* __restrict__ ei, const int* __restrict__ rank, const int* __restrict__ offs,
    const float* __restrict__ w1, const float* __restrict__ b1,
    const float* __restrict__ w2, const float* __restrict__ b2,
    const float* __restrict__ w3, const float* __restrict__ b3,
    float* __restrict__ msg)
{
    __shared__ float a2lds[4][64 * 33];
    int tid = threadIdx.x;
    int wave = tid >> 6, lane = tid & 63;
    int kg = lane >> 4, fr = lane & 15;
    float* lds = &a2lds[wave][0];
    const float2* h2v = reinterpret_cast<const float2*>(h2);

    float al0[8], al1[8], be0[8], be1[8], b1v[8];
    #pragma unroll
    for (int i = 0; i < 8; i++) {
        int k = kg * 8 + i;
        float c0a = w1[k], c1a = w1[32 + k];
        float c0b = w1[64 + k], c1b = w1[96 + k];
        al0[i] = c0a - c0b; al1[i] = c1a - c1b;
        be0[i] = c0b; be1[i] = c1b;
        b1v[i] = b1[k];
    }
    short8 bhi0, blo0, bhi1, blo1;
    #pragma unroll
    for (int i = 0; i < 8; i++) {
        int k = kg * 8 + i;
        float w0 = w2[k * 32 + fr];
        float w1c = w2[k * 32 + fr + 16];
        unsigned short h0 = bf16_rne(w0);
        bhi0[i] = (short)h0; blo0[i] = (short)bf16_rne(w0 - bf16_f32(h0));
        unsigned short h1 = bf16_rne(w1c);
        bhi1[i] = (short)h1; blo1[i] = (short)bf16_rne(w1c - bf16_f32(h1));
    }
    float b2v0 = b2[fr], b2v1 = b2[fr + 16];

    int g = blockIdx.x * 4 + wave;
    int base = g * 64;
    int dd0, dd1, dd2, dd3, ss0, ss1, ss2, ss3;
    {
        int e0 = base + fr, e1 = base + 16 + fr, e2 = base + 32 + fr, e3 = base + 48 + fr;
        dd0 = ei[N_EDGES + e0]; dd1 = ei[N_EDGES + e1];
        dd2 = ei[N_EDGES + e2]; dd3 = ei[N_EDGES + e3];
        ss0 = ei[e0]; ss1 = ei[e1]; ss2 = ei[e2]; ss3 = ei[e3];
    }
    int rk = rank[base + lane];
    int dsv = kg == 0 ? dd0 : kg == 1 ? dd1 : kg == 2 ? dd2 : dd3;
    int ofs = offs[dsv];
    float2 yd0 = h2v[dd0], ys0 = h2v[ss0];
    float2 yd1 = h2v[dd1], ys1 = h2v[ss1];
    float2 yd2 = h2v[dd2], ys2 = h2v[ss2];
    float2 yd3 = h2v[dd3], ys3 = h2v[ss3];

    while (true) {
        int gn = g + GSTRIDE;
        bool hn = gn < NGROUPS;
        int basen = gn * 64;
        int nrk = 0, nofs = 0;
        int ndd0=0,ndd1=0,ndd2=0,ndd3=0,nss0=0,nss1=0,nss2=0,nss3=0;
        if (hn) {
            int f0 = basen + fr, f1 = basen + 16 + fr, f2 = basen + 32 + fr, f3 = basen + 48 + fr;
            ndd0 = ei[N_EDGES + f0]; ndd1 = ei[N_EDGES + f1];
            ndd2 = ei[N_EDGES + f2]; ndd3 = ei[N_EDGES + f3];
            nss0 = ei[f0]; nss1 = ei[f1]; nss2 = ei[f2]; nss3 = ei[f3];
            nrk = rank[basen + lane];
        }

        #pragma unroll
        for (int t = 0; t < 4; t++) {
            float2 yd = t == 0 ? yd0 : t == 1 ? yd1 : t == 2 ? yd2 : yd3;
            float2 ys = t == 0 ? ys0 : t == 1 ? ys1 : t == 2 ? ys2 : ys3;
            float a[8];
            #pragma unroll
            for (int i = 0; i < 8; i++) {
                float pre = b1v[i];
                pre = fmaf(al0[i], yd.x, pre);
                pre = fmaf(al1[i], yd.y, pre);
                pre = fmaf(be0[i], ys.x, pre);
                pre = fmaf(be1[i], ys.y, pre);
                a[i] = fmaxf(pre, 0.f);
            }
            PackU ph, pl;
            #pragma unroll
            for (int j = 0; j < 4; j++) ph.u[j] = cvtpk_bf16(a[2*j], a[2*j+1]);
            #pragma unroll
            for (int j = 0; j < 4; j++) {
                float hlo = __uint_as_float(ph.u[j] << 16);
                float hhi = __uint_as_float(ph.u[j] & 0xffff0000u);
                pl.u[j] = cvtpk_bf16(a[2*j] - hlo, a[2*j+1] - hhi);
            }
            short8 ahi = ph.s, alo = pl.s;

            f32x4 acc0 = {0.f, 0.f, 0.f, 0.f}, acc1 = {0.f, 0.f, 0.f, 0.f};
            acc0 = __builtin_amdgcn_mfma_f32_16x16x32_bf16(alo, bhi0, acc0, 0, 0, 0);
            acc0 = __builtin_amdgcn_mfma_f32_16x16x32_bf16(ahi, blo0, acc0, 0, 0, 0);
            acc0 = __builtin_amdgcn_mfma_f32_16x16x32_bf16(ahi, bhi0, acc0, 0, 0, 0);
            acc1 = __builtin_amdgcn_mfma_f32_16x16x32_bf16(alo, bhi1, acc1, 0, 0, 0);
            acc1 = __builtin_amdgcn_mfma_f32_16x16x32_bf16(ahi, blo1, acc1, 0, 0, 0);
            acc1 = __builtin_amdgcn_mfma_f32_16x16x32_bf16(ahi, bhi1, acc1, 0, 0, 0);
            #pragma unroll
            for (int r = 0; r < 4; r++) {
                int er = t * 16 + kg * 4 + r;
                lds[er * 33 + fr]      = fmaxf(acc0[r] + b2v0, 0.f);
                lds[er * 33 + fr + 16] = fmaxf(acc1[r] + b2v1, 0.f);
            }
        }

        if (hn) {
            yd0 = h2v[ndd0]; ys0 = h2v[nss0];
            yd1 = h2v[ndd1]; ys1 = h2v[nss1];
            yd2 = h2v[ndd2]; ys2 = h2v[nss2];
            yd3 = h2v[ndd3]; ys3 = h2v[nss3];
            int ndsv = kg == 0 ? ndd0 : kg == 1 ? ndd1 : kg == 2 ? ndd2 : ndd3;
            nofs = offs[ndsv];
        }

        asm volatile("s_waitcnt lgkmcnt(0)" ::: "memory");

        float o0 = b3[0], o1 = b3[1], o2 = b3[2], o3 = b3[3];
        #pragma unroll
        for (int j = 0; j < 32; j++) {
            float aj = lds[lane * 33 + j];
            o0 = fmaf(aj, w3[4 * j],     o0);
            o1 = fmaf(aj, w3[4 * j + 1], o1);
            o2 = fmaf(aj, w3[4 * j + 2], o2);
            o3 = fmaf(aj, w3[4 * j + 3], o3);
        }
        reinterpret_cast<float4*>(msg)[ofs + rk] = make_float4(o0, o1, o2, o3);

        if (!hn) break;
        rk = nrk; ofs = nofs; g = gn;
    }
}

__global__ void agg2_kernel(const float* __restrict__ msg, const int* __restrict__ offs,
                            const int* __restrict__ cnt, float* __restrict__ out) {
    int lane = threadIdx.x & 63;
    int wave = threadIdx.x >> 6;
    int node = blockIdx.x * 8 + wave * 2 + (lane >> 5);
    int sub = lane & 31;
    if (node >= N_NODES) return;
    int base = offs[node];
    int deg  = cnt[node];
    float s0 = 0.f, s1 = 0.f, s2 = 0.f, s3 = 0.f;
    for (int k = sub; k < deg; k += 32) {
        float4 m = reinterpret_cast<const float4*>(msg)[base + k];
        s0 += m.x; s1 += m.y; s2 += m.z; s3 += m.w;
    }
    #pragma unroll
    for (int o = 16; o > 0; o >>= 1) {
        s0 += __shfl_down(s0, o, 32); s1 += __shfl_down(s1, o, 32);
        s2 += __shfl_down(s2, o, 32); s3 += __shfl_down(s3, o, 32);
    }
    if (sub == 0) {
        float c = fmaxf((float)deg, 1.f);
        reinterpret_cast<float4*>(out)[node] = make_float4(s0/c, s1/c, s2/c, s3/c);
    }
}

extern "C" void kernel_launch(void* const* d_in, const int* in_sizes, int n_in,
                              void* d_out, int out_size, void* d_ws, size_t ws_size,
                              hipStream_t stream) {
    const float* x        = (const float*)d_in[0];
    const int*   ei       = (const int*)  d_in[1];
    const float* bn_gamma = (const float*)d_in[2];
    const float* bn_beta  = (const float*)d_in[3];
    const float* enc_w1   = (const float*)d_in[4];
    const float* enc_b1   = (const float*)d_in[5];
    const float* enc_w2   = (const float*)d_in[6];
    const float* enc_b2   = (const float*)d_in[7];
    const float* enc_w3   = (const float*)d_in[8];
    const float* enc_b3   = (const float*)d_in[9];
    const float* dec_w1   = (const float*)d_in[10];
    const float* dec_b1   = (const float*)d_in[11];
    const float* dec_w2   = (const float*)d_in[12];
    const float* dec_b2   = (const float*)d_in[13];
    const float* dec_w3   = (const float*)d_in[14];
    const float* dec_b3   = (const float*)d_in[15];

    float* wsf   = (float*)d_ws;
    int*   wsi   = (int*)d_ws;
    float* stats = wsf + O_STATS;
    int*   cnt   = wsi + O_CNT;
    int*   offs  = wsi + O_OFFS;
    int*   bsums = wsi + O_BSUM;
    int*   rank  = wsi + O_RANK;
    float* h     = wsf + O_H;
    float* h2    = wsf + O_H2;
    float* msg   = wsf + O_MSG;
    float* out   = (float*)d_out;

    hipMemsetAsync(d_ws, 0, (size_t)(8 + N_NODES) * sizeof(float), stream);

    const int nodeBlocks = (N_NODES + 255) / 256;
    const int edgeBlocks = (N_EDGES + 255) / 256;
    const int aggBlocks  = (N_NODES + 7) / 8;

    bn_stats_kernel<<<STATS_BLOCKS, 256, 0, stream>>>(x, stats);
    bn_apply_kernel<<<nodeBlocks, 256, 0, stream>>>(x, stats, bn_gamma, bn_beta, h);
    rank_kernel<<<edgeBlocks, 256, 0, stream>>>(ei, cnt, rank);
    scan_block_kernel<<<SCAN_BLOCKS, 256, 0, stream>>>(cnt, offs, bsums);
    scan_mid_kernel<<<1, 512, 0, stream>>>(bsums);
    scan_add_kernel<<<SCAN_BLOCKS, 256, 0, stream>>>(offs, bsums);
    conv1_mfma_kernel<<<CONV_BLOCKS, 256, 0, stream>>>(h, ei, rank, offs,
                                                       enc_w1, enc_b1, enc_w2, enc_b2,
                                                       enc_w3, enc_b3, msg);
    agg1_kernel<<<aggBlocks, 256, 0, stream>>>(msg, offs, cnt, h2);
    conv2_mfma_kernel<<<CONV_BLOCKS, 256, 0, stream>>>(h2, ei, rank, offs,
                                                       dec_w1, dec_b1, dec_w2, dec_b2,
                                                       dec_w3, dec_b3, msg);
    agg2_kernel<<<aggBlocks, 256, 0, stream>>>(msg, offs, cnt, out);
}